// Round 3
// baseline (170.583 us; speedup 1.0000x reference)
//
#include <hip/hip_runtime.h>

#define N_NODES 100000
#define D 128
#define E_POS 262144
#define E_NEG 262144
#define E_TOT (E_POS + E_NEG)

typedef __attribute__((ext_vector_type(8))) short short8;  // 8 bf16 (4 VGPRs)
typedef __attribute__((ext_vector_type(4))) float f4;      // MFMA C/D frag

__device__ __forceinline__ unsigned f2bf_u(float f) {
    // round-to-nearest-even fp32 -> bf16 (inputs finite; no NaN path)
    unsigned u = __float_as_uint(f);
    return (u + 0x7fffu + ((u >> 16) & 1u)) >> 16;
}

// ---------------------------------------------------------------------------
// Prep: pack W1 (fp32 [256,128]) into bf16 MFMA-B-fragment layout:
//   Wf[((h*4+ks)*4+q)*128 + c][j] = bf16( W1[h*128 + ks*32 + q*8 + j][c] )
// so a lane's short8 B-frag is one aligned 16-B load, contiguous across the
// 16-lane group. Total 2*4*4*128*8 = 32768 bf16 = 64 KB (L2-resident).
// ---------------------------------------------------------------------------
__global__ __launch_bounds__(256) void pack_w1(
    const float* __restrict__ W1, unsigned short* __restrict__ Wf)
{
    const int tid = blockIdx.x * 256 + threadIdx.x;   // 4096 groups
    if (tid >= 4096) return;
    const int h  = tid >> 11;
    const int ks = (tid >> 9) & 3;
    const int q  = (tid >> 7) & 3;
    const int c  = tid & 127;
    const int kb = h * 128 + ks * 32 + q * 8;
    const float* src = W1 + (size_t)kb * D + c;
    unsigned short* dst = Wf + (size_t)tid * 8;
    unsigned short tmp[8];
#pragma unroll
    for (int j = 0; j < 8; ++j) tmp[j] = (unsigned short)f2bf_u(src[(size_t)j * D]);
    *(uint4*)dst = *(const uint4*)tmp;
}

// ---------------------------------------------------------------------------
// Phase 1 (bf16 MFMA): UVb[n][j] (bf16) =
//   j<128 : sum_k x[n][k]*W1[k][j] + b1[j]      (U)
//   j>=128: sum_k x[n][k]*W1[128+k][j-128]      (V)
// 256 thr = 4 waves; 64 rows x 256 cols per block; wave w -> col slice w*64.
// A loaded from x (float4 pairs, converted in-register); B from packed Wf
// (one dwordx4 per frag). Epilogue transposes through LDS for row-major
// dwordx4 stores.
// MFMA layouts (measured, m89/m91): A[m=lane&15][k=q*8+j],
// B[k=q*8+j][n=lane&15], C: col=lane&15, row=q*4+reg.
// ---------------------------------------------------------------------------
__global__ __launch_bounds__(256) void node_gemm_mfma(
    const float* __restrict__ x,            // [N, 128]
    const unsigned short* __restrict__ Wf,  // packed B frags
    const float* __restrict__ b1,           // [128]
    unsigned short* __restrict__ UVb)       // [N, 256] bf16
{
    __shared__ unsigned short Ls[64][264];  // 64 x 256 cols, +8 pad

    const int t    = threadIdx.x;
    const int w    = t >> 6;                // wave 0..3
    const int lane = t & 63;
    const int m16  = lane & 15;
    const int q    = lane >> 4;             // quad 0..3
    const int nb   = blockIdx.x * 64;
    const int h    = w >> 1;                // 0=U, 1=V
    const int cbase = (w & 1) * 64;

    f4 acc[4][4];
#pragma unroll
    for (int i = 0; i < 4; ++i)
#pragma unroll
        for (int j = 0; j < 4; ++j) acc[i][j] = (f4){0.f, 0.f, 0.f, 0.f};

    int rows[4];
#pragma unroll
    for (int rt = 0; rt < 4; ++rt) {
        int r = nb + rt * 16 + m16;
        rows[rt] = (r < N_NODES) ? r : (N_NODES - 1);  // clamp; store guarded
    }

#pragma unroll
    for (int ks = 0; ks < 4; ++ks) {
        const int k0 = ks * 32 + q * 8;     // this lane's 8 consecutive k
        short8 af[4], bfr[4];
#pragma unroll
        for (int rt = 0; rt < 4; ++rt) {
            const float* px = x + (size_t)rows[rt] * D + k0;
            const float4 a0 = *(const float4*)px;
            const float4 a1 = *(const float4*)(px + 4);
            short8 s;
            s[0] = (short)f2bf_u(a0.x); s[1] = (short)f2bf_u(a0.y);
            s[2] = (short)f2bf_u(a0.z); s[3] = (short)f2bf_u(a0.w);
            s[4] = (short)f2bf_u(a1.x); s[5] = (short)f2bf_u(a1.y);
            s[6] = (short)f2bf_u(a1.z); s[7] = (short)f2bf_u(a1.w);
            af[rt] = s;
        }
        const unsigned short* wfb =
            Wf + ((size_t)(((h * 4 + ks) * 4 + q) * 128 + cbase + m16)) * 8;
#pragma unroll
        for (int ct = 0; ct < 4; ++ct)
            bfr[ct] = *(const short8*)(wfb + (size_t)ct * 16 * 8);
#pragma unroll
        for (int rt = 0; rt < 4; ++rt)
#pragma unroll
            for (int ct = 0; ct < 4; ++ct)
                acc[rt][ct] = __builtin_amdgcn_mfma_f32_16x16x32_bf16(
                    af[rt], bfr[ct], acc[rt][ct], 0, 0, 0);
    }

    // b1 folds into the U half only (cols < 128 -> waves 0,1)
    float badd[4];
#pragma unroll
    for (int ct = 0; ct < 4; ++ct) {
        const int cg = w * 64 + ct * 16 + m16;
        badd[ct] = (h == 0) ? b1[cg] : 0.f;
    }

    // scatter C-frags (bf16) into LDS row-major
#pragma unroll
    for (int rt = 0; rt < 4; ++rt)
#pragma unroll
        for (int ct = 0; ct < 4; ++ct) {
            const int colg = w * 64 + ct * 16 + m16;
#pragma unroll
            for (int r = 0; r < 4; ++r) {
                const int row = rt * 16 + q * 4 + r;
                Ls[row][colg] =
                    (unsigned short)f2bf_u(acc[rt][ct][r] + badd[ct]);
            }
        }
    __syncthreads();

    // coalesced bf16 store: thread t -> row t>>2, 64-col chunk (t&3)
    const int r  = t >> 2;
    const int c0 = (t & 3) * 64;
    const int grow = nb + r;
    if (grow < N_NODES) {
        const uint4* s = (const uint4*)&Ls[r][c0];
        uint4* d = (uint4*)(UVb + (size_t)grow * 256 + c0);
#pragma unroll
        for (int i = 0; i < 8; ++i) d[i] = s[i];
    }
}

// ---------------------------------------------------------------------------
// Phase 2: out[e] = relu(U[src]+V[tar]) . W2 + b2, UV in bf16.
// 16 lanes per edge-pair slot; each 16-lane group handles 2 consecutive
// edges (4 independent 16-B gathers in flight -> 2x MLP, interleaved
// shuffle-reduce chains). 8 edge-pairs per wave-group... 16 groups/block.
// ---------------------------------------------------------------------------
__global__ __launch_bounds__(256) void edge_score_bf(
    const unsigned short* __restrict__ UVb,
    const int* __restrict__ pos,            // [2, E_POS]
    const int* __restrict__ neg,            // [2, E_NEG]
    const float* __restrict__ W2,           // [128]
    const float* __restrict__ b2,           // [1]
    float* __restrict__ out)                // [E_TOT]
{
    const int t    = threadIdx.x;
    const int lane = t & 63;
    const int l16  = lane & 15;
    const int sub  = lane >> 4;
    const int w    = t >> 6;
    const int g    = blockIdx.x * 16 + w * 4 + sub;   // edge-pair group
    const int e0   = g * 2;                           // E_POS even: no straddle
    const int e1   = e0 + 1;

    int s0, t0, s1, t1;
    if (e0 < E_POS) {
        s0 = pos[e0];        s1 = pos[e1];
        t0 = pos[E_POS + e0]; t1 = pos[E_POS + e1];
    } else {
        const int f = e0 - E_POS;
        s0 = neg[f];          s1 = neg[f + 1];
        t0 = neg[E_NEG + f];  t1 = neg[E_NEG + f + 1];
    }

    const uint4 u0 = *(const uint4*)(UVb + (size_t)s0 * 256 + l16 * 8);
    const uint4 v0 = *(const uint4*)(UVb + (size_t)t0 * 256 + 128 + l16 * 8);
    const uint4 u1 = *(const uint4*)(UVb + (size_t)s1 * 256 + l16 * 8);
    const uint4 v1 = *(const uint4*)(UVb + (size_t)t1 * 256 + 128 + l16 * 8);
    const float4 wa = *(const float4*)(W2 + l16 * 8);
    const float4 wb = *(const float4*)(W2 + l16 * 8 + 4);

#define BF_LO(uv) __uint_as_float((uv) << 16)
#define BF_HI(uv) __uint_as_float((uv) & 0xffff0000u)
#define ACC8(P, U, V)                                                   \
    P = fmaf(fmaxf(BF_LO(U.x) + BF_LO(V.x), 0.f), wa.x, P);             \
    P = fmaf(fmaxf(BF_HI(U.x) + BF_HI(V.x), 0.f), wa.y, P);             \
    P = fmaf(fmaxf(BF_LO(U.y) + BF_LO(V.y), 0.f), wa.z, P);             \
    P = fmaf(fmaxf(BF_HI(U.y) + BF_HI(V.y), 0.f), wa.w, P);             \
    P = fmaf(fmaxf(BF_LO(U.z) + BF_LO(V.z), 0.f), wb.x, P);             \
    P = fmaf(fmaxf(BF_HI(U.z) + BF_HI(V.z), 0.f), wb.y, P);             \
    P = fmaf(fmaxf(BF_LO(U.w) + BF_LO(V.w), 0.f), wb.z, P);             \
    P = fmaf(fmaxf(BF_HI(U.w) + BF_HI(V.w), 0.f), wb.w, P);

    float p0 = 0.f, p1 = 0.f;
    ACC8(p0, u0, v0)
    ACC8(p1, u1, v1)
#undef ACC8
#undef BF_LO
#undef BF_HI

#pragma unroll
    for (int off = 8; off; off >>= 1) {
        p0 += __shfl_xor(p0, off, 64);
        p1 += __shfl_xor(p1, off, 64);
    }

    if (l16 == 0) {
        const float bb = b2[0];
        out[e0] = p0 + bb;
        out[e1] = p1 + bb;
    }
}

// ---------------------------------------------------------------------------
// Fallback (ws too small): one wave per edge, direct fp32 compute.
// ---------------------------------------------------------------------------
__global__ __launch_bounds__(64) void edge_naive(
    const float* __restrict__ x,
    const int* __restrict__ pos, const int* __restrict__ neg,
    const float* __restrict__ W1, const float* __restrict__ b1,
    const float* __restrict__ W2, const float* __restrict__ b2,
    float* __restrict__ out)
{
    const int lane = threadIdx.x;
    for (int e = blockIdx.x; e < E_TOT; e += gridDim.x) {
        int src, tar;
        if (e < E_POS) { src = pos[e]; tar = pos[E_POS + e]; }
        else { int e2 = e - E_POS; src = neg[e2]; tar = neg[E_NEG + e2]; }
        const float* xsrc = x + (size_t)src * D;
        const float* xtar = x + (size_t)tar * D;
        int j = lane * 2;
        float h0 = b1[j], h1 = b1[j + 1];
        for (int k = 0; k < D; ++k) {
            float a = xsrc[k], b = xtar[k];
            h0 = fmaf(a, W1[(size_t)k * D + j],       h0);
            h0 = fmaf(b, W1[(size_t)(k + D) * D + j], h0);
            h1 = fmaf(a, W1[(size_t)k * D + j + 1],       h1);
            h1 = fmaf(b, W1[(size_t)(k + D) * D + j + 1], h1);
        }
        float p = fmaf(fmaxf(h0, 0.f), W2[j], fmaxf(h1, 0.f) * W2[j + 1]);
#pragma unroll
        for (int off = 32; off > 0; off >>= 1) p += __shfl_xor(p, off, 64);
        if (lane == 0) out[e] = p + b2[0];
    }
}

extern "C" void kernel_launch(void* const* d_in, const int* in_sizes, int n_in,
                              void* d_out, int out_size, void* d_ws, size_t ws_size,
                              hipStream_t stream) {
    const float* x   = (const float*)d_in[0];
    const int*   pos = (const int*)d_in[1];
    const int*   neg = (const int*)d_in[2];
    const float* W1  = (const float*)d_in[3];
    const float* b1  = (const float*)d_in[4];
    const float* W2  = (const float*)d_in[5];
    const float* b2  = (const float*)d_in[6];
    float* out = (float*)d_out;

    const size_t uv_bytes = (size_t)N_NODES * 256 * sizeof(unsigned short);
    const size_t wf_bytes = 32768 * sizeof(unsigned short);
    if (ws_size >= uv_bytes + wf_bytes) {
        unsigned short* UVb = (unsigned short*)d_ws;
        unsigned short* Wfr = (unsigned short*)((char*)d_ws + uv_bytes);
        pack_w1<<<16, 256, 0, stream>>>((const float*)d_in[3], Wfr);
        node_gemm_mfma<<<(N_NODES + 63) / 64, 256, 0, stream>>>(x, Wfr, b1, UVb);
        edge_score_bf<<<E_TOT / 32, 256, 0, stream>>>(UVb, pos, neg, W2, b2, out);
    } else {
        edge_naive<<<8192, 64, 0, stream>>>(x, pos, neg, W1, b1, W2, b2, out);
    }
}

// Round 4
// 159.582 us; speedup vs baseline: 1.0689x; 1.0689x over previous
//
#include <hip/hip_runtime.h>

#define N_NODES 100000
#define D 128
#define E_POS 262144
#define E_NEG 262144
#define E_TOT (E_POS + E_NEG)

typedef __attribute__((ext_vector_type(8))) short short8;  // 8 bf16 (4 VGPRs)
typedef __attribute__((ext_vector_type(4))) float f4;      // MFMA C/D frag

__device__ __forceinline__ unsigned f2bf_u(float f) {
    // round-to-nearest-even fp32 -> bf16 (inputs finite; no NaN path)
    unsigned u = __float_as_uint(f);
    return (u + 0x7fffu + ((u >> 16) & 1u)) >> 16;
}

// ---------------------------------------------------------------------------
// Prep: pack W1 (fp32 [256,128]) into bf16 MFMA-B-fragment layout:
//   Wf[((h*4+ks)*4+q)*128 + c][j] = bf16( W1[h*128 + ks*32 + q*8 + j][c] )
// One aligned 16-B load per lane-frag. 64 KB total (L2-resident).
// ---------------------------------------------------------------------------
__global__ __launch_bounds__(256) void pack_w1(
    const float* __restrict__ W1, unsigned short* __restrict__ Wf)
{
    const int tid = blockIdx.x * 256 + threadIdx.x;   // 4096 groups
    if (tid >= 4096) return;
    const int h  = tid >> 11;
    const int ks = (tid >> 9) & 3;
    const int q  = (tid >> 7) & 3;
    const int c  = tid & 127;
    const int kb = h * 128 + ks * 32 + q * 8;
    const float* src = W1 + (size_t)kb * D + c;
    unsigned short tmp[8];
#pragma unroll
    for (int j = 0; j < 8; ++j) tmp[j] = (unsigned short)f2bf_u(src[(size_t)j * D]);
    *(uint4*)(Wf + (size_t)tid * 8) = *(const uint4*)tmp;
}

// ---------------------------------------------------------------------------
// Phase 1 (bf16 MFMA): UVb[n][j] (bf16) =
//   j<128 : sum_k x[n][k]*W1[k][j] + b1[j]      (U)
//   j>=128: sum_k x[n][k]*W1[128+k][j-128]      (V)
// 256 thr = 4 waves; 64 rows x 256 cols; wave w -> col slice w*64.
// x staged to LDS as bf16 with coalesced float4 loads; A-frags come out as
// single ds_read_b128. B from packed Wf (one dwordx4/frag, L2-hit).
// Epilogue reuses the LDS buffer to transpose C-frags for row-major stores.
// MFMA layouts (measured, m89/m91): A[m=lane&15][k=q*8+j],
// B[k=q*8+j][n=lane&15], C: col=lane&15, row=q*4+reg.
// ---------------------------------------------------------------------------
#define XRS 136   // staging row stride in shorts (272 B: 16-B aligned)
#define ERS 264   // epilogue row stride in shorts (528 B: 16-B aligned)

__global__ __launch_bounds__(256) void node_gemm_mfma(
    const float* __restrict__ x,            // [N, 128]
    const unsigned short* __restrict__ Wf,  // packed B frags
    const float* __restrict__ b1,           // [128]
    unsigned short* __restrict__ UVb)       // [N, 256] bf16
{
    __shared__ unsigned short Ls[64 * ERS]; // 33792 B; staging uses front 17 KB

    const int t    = threadIdx.x;
    const int w    = t >> 6;                // wave 0..3
    const int lane = t & 63;
    const int m16  = lane & 15;
    const int q    = lane >> 4;             // quad 0..3
    const int nb   = blockIdx.x * 64;
    const int h    = w >> 1;                // 0=U, 1=V
    const int cbase = (w & 1) * 64;

    // ---- stage x[64][128] -> bf16 LDS, coalesced ----
#pragma unroll
    for (int i = 0; i < 8; ++i) {
        const int s   = t + i * 256;        // slot of 4 floats, 0..2047
        const int row = s >> 5;
        const int c4  = s & 31;
        const int gr  = nb + row;
        float4 a = make_float4(0.f, 0.f, 0.f, 0.f);
        if (gr < N_NODES) a = *(const float4*)(x + (size_t)gr * D + c4 * 4);
        const unsigned p0 = (f2bf_u(a.y) << 16) | f2bf_u(a.x);
        const unsigned p1 = (f2bf_u(a.w) << 16) | f2bf_u(a.z);
        *(uint2*)&Ls[row * XRS + c4 * 4] = make_uint2(p0, p1);
    }
    __syncthreads();

    f4 acc[4][4];
#pragma unroll
    for (int i = 0; i < 4; ++i)
#pragma unroll
        for (int j = 0; j < 4; ++j) acc[i][j] = (f4){0.f, 0.f, 0.f, 0.f};

    int arow[4];
#pragma unroll
    for (int rt = 0; rt < 4; ++rt) arow[rt] = (rt * 16 + m16) * XRS;

#pragma unroll
    for (int ks = 0; ks < 4; ++ks) {
        const int kcol = ks * 32 + q * 8;
        short8 af[4], bfr[4];
#pragma unroll
        for (int rt = 0; rt < 4; ++rt)
            af[rt] = *(const short8*)&Ls[arow[rt] + kcol];
        const unsigned short* wfb =
            Wf + ((size_t)(((h * 4 + ks) * 4 + q) * 128 + cbase + m16)) * 8;
#pragma unroll
        for (int ct = 0; ct < 4; ++ct)
            bfr[ct] = *(const short8*)(wfb + (size_t)ct * 16 * 8);
#pragma unroll
        for (int rt = 0; rt < 4; ++rt)
#pragma unroll
            for (int ct = 0; ct < 4; ++ct)
                acc[rt][ct] = __builtin_amdgcn_mfma_f32_16x16x32_bf16(
                    af[rt], bfr[ct], acc[rt][ct], 0, 0, 0);
    }

    // b1 folds into the U half only (cols < 128 -> waves 0,1)
    float badd[4];
#pragma unroll
    for (int ct = 0; ct < 4; ++ct) {
        const int cg = w * 64 + ct * 16 + m16;
        badd[ct] = (h == 0) ? b1[cg] : 0.f;
    }

    __syncthreads();   // all A-frag reads done before we overwrite Ls

    // scatter C-frags (bf16) into LDS row-major
#pragma unroll
    for (int rt = 0; rt < 4; ++rt)
#pragma unroll
        for (int ct = 0; ct < 4; ++ct) {
            const int colg = w * 64 + ct * 16 + m16;
#pragma unroll
            for (int r = 0; r < 4; ++r) {
                const int row = rt * 16 + q * 4 + r;
                Ls[row * ERS + colg] =
                    (unsigned short)f2bf_u(acc[rt][ct][r] + badd[ct]);
            }
        }
    __syncthreads();

    // coalesced bf16 store: thread t -> row t>>2, 64-col chunk (t&3)
    const int r  = t >> 2;
    const int c0 = (t & 3) * 64;
    const int grow = nb + r;
    if (grow < N_NODES) {
        const uint4* s = (const uint4*)&Ls[r * ERS + c0];
        uint4* d = (uint4*)(UVb + (size_t)grow * 256 + c0);
#pragma unroll
        for (int i = 0; i < 8; ++i) d[i] = s[i];
    }
}

// ---------------------------------------------------------------------------
// Phase 2: out[e] = relu(U[src]+V[tar]) . W2 + b2, UV in bf16.
// Block = 256 thr, 512 edges. Indices staged coalesced into LDS once.
// Each 16-lane group: 4 edges/iter, 8 independent 16-B gathers, 8 iters,
// unroll 2 -> up to 16 gathers in flight. float4 output stores.
// Block/edge ranges never straddle pos/neg (E_POS = 512*512).
// ---------------------------------------------------------------------------
__global__ __launch_bounds__(256) void edge_score_bf(
    const unsigned short* __restrict__ UVb,
    const int* __restrict__ pos,            // [2, E_POS]
    const int* __restrict__ neg,            // [2, E_NEG]
    const float* __restrict__ W2,           // [128]
    const float* __restrict__ b2,           // [1]
    float* __restrict__ out)                // [E_TOT]
{
    __shared__ int sidx[512], tidx[512];

    const int t   = threadIdx.x;
    const int bid = blockIdx.x;
    const int e0  = bid * 512;                       // global edge base
    const int* eidx = (bid < 512) ? pos : neg;
    const int lb    = (bid < 512) ? e0 : e0 - E_POS; // base within pos/neg

    {
        const int2 sp = *(const int2*)(eidx + lb + 2 * t);
        const int2 tp = *(const int2*)(eidx + E_POS + lb + 2 * t);
        *(int2*)&sidx[2 * t] = sp;
        *(int2*)&tidx[2 * t] = tp;
    }
    __syncthreads();

    const int g   = t >> 4;
    const int l16 = t & 15;
    const float4 wa = *(const float4*)(W2 + l16 * 8);
    const float4 wb = *(const float4*)(W2 + l16 * 8 + 4);
    const float bb = b2[0];

#define BF_LO(uv) __uint_as_float((uv) << 16)
#define BF_HI(uv) __uint_as_float((uv) & 0xffff0000u)
#define ACC8(P, U, V)                                                   \
    P = fmaf(fmaxf(BF_LO(U.x) + BF_LO(V.x), 0.f), wa.x, P);             \
    P = fmaf(fmaxf(BF_HI(U.x) + BF_HI(V.x), 0.f), wa.y, P);             \
    P = fmaf(fmaxf(BF_LO(U.y) + BF_LO(V.y), 0.f), wa.z, P);             \
    P = fmaf(fmaxf(BF_HI(U.y) + BF_HI(V.y), 0.f), wa.w, P);             \
    P = fmaf(fmaxf(BF_LO(U.z) + BF_LO(V.z), 0.f), wb.x, P);             \
    P = fmaf(fmaxf(BF_HI(U.z) + BF_HI(V.z), 0.f), wb.y, P);             \
    P = fmaf(fmaxf(BF_LO(U.w) + BF_LO(V.w), 0.f), wb.z, P);             \
    P = fmaf(fmaxf(BF_HI(U.w) + BF_HI(V.w), 0.f), wb.w, P);

#pragma unroll 2
    for (int k = 0; k < 8; ++k) {
        const int el = k * 64 + g * 4;      // 4 consecutive local edges
        const int4 ss = *(const int4*)&sidx[el];
        const int4 tt = *(const int4*)&tidx[el];
        const uint4 U0 = *(const uint4*)(UVb + (size_t)ss.x * 256 + l16 * 8);
        const uint4 U1 = *(const uint4*)(UVb + (size_t)ss.y * 256 + l16 * 8);
        const uint4 U2 = *(const uint4*)(UVb + (size_t)ss.z * 256 + l16 * 8);
        const uint4 U3 = *(const uint4*)(UVb + (size_t)ss.w * 256 + l16 * 8);
        const uint4 V0 = *(const uint4*)(UVb + (size_t)tt.x * 256 + 128 + l16 * 8);
        const uint4 V1 = *(const uint4*)(UVb + (size_t)tt.y * 256 + 128 + l16 * 8);
        const uint4 V2 = *(const uint4*)(UVb + (size_t)tt.z * 256 + 128 + l16 * 8);
        const uint4 V3 = *(const uint4*)(UVb + (size_t)tt.w * 256 + 128 + l16 * 8);

        float p0 = 0.f, p1 = 0.f, p2 = 0.f, p3 = 0.f;
        ACC8(p0, U0, V0)
        ACC8(p1, U1, V1)
        ACC8(p2, U2, V2)
        ACC8(p3, U3, V3)

#pragma unroll
        for (int off = 8; off; off >>= 1) {
            p0 += __shfl_xor(p0, off, 64);
            p1 += __shfl_xor(p1, off, 64);
            p2 += __shfl_xor(p2, off, 64);
            p3 += __shfl_xor(p3, off, 64);
        }

        if (l16 == 0)
            *(float4*)(out + e0 + el) =
                make_float4(p0 + bb, p1 + bb, p2 + bb, p3 + bb);
    }
#undef ACC8
#undef BF_LO
#undef BF_HI
}

// ---------------------------------------------------------------------------
// Fallback (ws too small): one wave per edge, direct fp32 compute.
// ---------------------------------------------------------------------------
__global__ __launch_bounds__(64) void edge_naive(
    const float* __restrict__ x,
    const int* __restrict__ pos, const int* __restrict__ neg,
    const float* __restrict__ W1, const float* __restrict__ b1,
    const float* __restrict__ W2, const float* __restrict__ b2,
    float* __restrict__ out)
{
    const int lane = threadIdx.x;
    for (int e = blockIdx.x; e < E_TOT; e += gridDim.x) {
        int src, tar;
        if (e < E_POS) { src = pos[e]; tar = pos[E_POS + e]; }
        else { int e2 = e - E_POS; src = neg[e2]; tar = neg[E_NEG + e2]; }
        const float* xsrc = x + (size_t)src * D;
        const float* xtar = x + (size_t)tar * D;
        int j = lane * 2;
        float h0 = b1[j], h1 = b1[j + 1];
        for (int k = 0; k < D; ++k) {
            float a = xsrc[k], b = xtar[k];
            h0 = fmaf(a, W1[(size_t)k * D + j],       h0);
            h0 = fmaf(b, W1[(size_t)(k + D) * D + j], h0);
            h1 = fmaf(a, W1[(size_t)k * D + j + 1],       h1);
            h1 = fmaf(b, W1[(size_t)(k + D) * D + j + 1], h1);
        }
        float p = fmaf(fmaxf(h0, 0.f), W2[j], fmaxf(h1, 0.f) * W2[j + 1]);
#pragma unroll
        for (int off = 32; off > 0; off >>= 1) p += __shfl_xor(p, off, 64);
        if (lane == 0) out[e] = p + b2[0];
    }
}

extern "C" void kernel_launch(void* const* d_in, const int* in_sizes, int n_in,
                              void* d_out, int out_size, void* d_ws, size_t ws_size,
                              hipStream_t stream) {
    const float* x   = (const float*)d_in[0];
    const int*   pos = (const int*)d_in[1];
    const int*   neg = (const int*)d_in[2];
    const float* W1  = (const float*)d_in[3];
    const float* b1  = (const float*)d_in[4];
    const float* W2  = (const float*)d_in[5];
    const float* b2  = (const float*)d_in[6];
    float* out = (float*)d_out;

    const size_t uv_bytes = (size_t)N_NODES * 256 * sizeof(unsigned short);
    const size_t wf_bytes = 32768 * sizeof(unsigned short);
    if (ws_size >= uv_bytes + wf_bytes) {
        unsigned short* UVb = (unsigned short*)d_ws;
        unsigned short* Wfr = (unsigned short*)((char*)d_ws + uv_bytes);
        pack_w1<<<16, 256, 0, stream>>>(W1, Wfr);
        node_gemm_mfma<<<(N_NODES + 63) / 64, 256, 0, stream>>>(x, Wfr, b1, UVb);
        edge_score_bf<<<E_TOT / 512, 256, 0, stream>>>(UVb, pos, neg, W2, b2, out);
    } else {
        edge_naive<<<8192, 64, 0, stream>>>(x, pos, neg, W1, b1, W2, b2, out);
    }
}